// Round 1
// 329.966 us; speedup vs baseline: 1.0593x; 1.0593x over previous
//
#include <hip/hip_runtime.h>
#include <hip/hip_bf16.h>
#include <stdint.h>

// ---------------------------------------------------------------------------
// MultiHeadAttention fused forward, MI355X (gfx950)
//   B=4, S=2048, D_MODEL=1024, H=16, depth=64; fp32 I/O, bf16 MFMA internal.
// R4 (attention rewrite):
//   - P never touches LDS: PV k-slots permuted (k = 32kc + 16(j>>2) + 4quad
//     + (j&3)) so the PV B-fragment is exactly the lane's own S^T registers;
//     V A-fragment gathered with the same permutation (2x ds_read_b64).
//   - l-sum via ones-MFMA (l = 1^T P): 4 MFMA/kt replace 32 VALU adds/kt and
//     the final cross-quad shuffles (MFMA broadcasts l to all lanes).
//   - K/V double-buffered (freed Pt LDS pays for it; still 32 KB/block),
//     T3-minimal pipeline: {STAGE(next); compute(cur); vmcnt(0); barrier} --
//     1 barrier/tile instead of 2, staging hides under compute.
// ---------------------------------------------------------------------------

#define SEQ    2048
#define DEPTH  64
#define HEADS  16
#define NMODEL 1024
#define MROWS  8192   // B*S

typedef __bf16 bf16x8 __attribute__((ext_vector_type(8)));
typedef __bf16 bf16x4 __attribute__((ext_vector_type(4)));
typedef float  f32x4  __attribute__((ext_vector_type(4)));

__device__ __forceinline__ unsigned short f32_bf16(float f) {
    union { float f; unsigned int u; } c; c.f = f;
    unsigned int u = c.u + 0x7FFFu + ((c.u >> 16) & 1u);   // RNE
    return (unsigned short)(u >> 16);
}

__device__ __forceinline__ void gload16(const unsigned short* g, unsigned short* l) {
    __builtin_amdgcn_global_load_lds(
        (const __attribute__((address_space(1))) unsigned int*)g,
        (__attribute__((address_space(3))) unsigned int*)l, 16, 0, 0);
}

// ---------------------------------------------------------------------------
__global__ __launch_bounds__(256) void cvt3_kernel(
    const float* __restrict__ a, const float* __restrict__ b, const float* __restrict__ c,
    unsigned short* __restrict__ oa, unsigned short* __restrict__ ob,
    unsigned short* __restrict__ oc, int n4)
{
    const float* in; unsigned short* out;
    if (blockIdx.y == 0) { in = a; out = oa; }
    else if (blockIdx.y == 1) { in = b; out = ob; }
    else { in = c; out = oc; }
    int i = blockIdx.x * 256 + threadIdx.x;
    if (i < n4) {
        float4 f = ((const float4*)in)[i];
        ushort4 o;
        o.x = f32_bf16(f.x); o.y = f32_bf16(f.y);
        o.z = f32_bf16(f.z); o.w = f32_bf16(f.w);
        ((ushort4*)out)[i] = o;
    }
}

__global__ __launch_bounds__(256) void cvt4_kernel(
    const float* __restrict__ a, const float* __restrict__ b,
    const float* __restrict__ c, const float* __restrict__ d,
    unsigned short* __restrict__ oa, unsigned short* __restrict__ ob,
    unsigned short* __restrict__ oc, unsigned short* __restrict__ od, int n4)
{
    const float* in; unsigned short* out;
    if (blockIdx.y == 0) { in = a; out = oa; }
    else if (blockIdx.y == 1) { in = b; out = ob; }
    else if (blockIdx.y == 2) { in = c; out = oc; }
    else { in = d; out = od; }
    int i = blockIdx.x * 256 + threadIdx.x;
    if (i < n4) {
        float4 f = ((const float4*)in)[i];
        ushort4 o;
        o.x = f32_bf16(f.x); o.y = f32_bf16(f.y);
        o.z = f32_bf16(f.z); o.w = f32_bf16(f.w);
        ((ushort4*)out)[i] = o;
    }
}

// ---------------------------------------------------------------------------
// 128x128 tile GEMM core, BK=64, XOR-swizzled LDS.
// C[m,n] = sum_k A[m,k]*W[n,k]; K = 1024.
// mode 0: fp32 out row-major [.,NMODEL], bias[col]
// mode 1: bf16 out head-split [B,H,S,64], (acc+bias[col])*scale
// mode 2: bf16 out row-major [.,MROWS], bias[row]   (V^T)
__device__ __forceinline__ void gemm128_core(
    const unsigned short* __restrict__ A, const unsigned short* __restrict__ W,
    const float* __restrict__ bias, void* __restrict__ outp,
    int mode, float scale, int m0, int n0,
    unsigned short* Alds, unsigned short* Blds)
{
    const int tid  = threadIdx.x;
    const int wave = tid >> 6, lane = tid & 63;
    const int l15  = lane & 15, quad = lane >> 4;
    const int wm   = wave & 1,  wn   = wave >> 1;
    const int swz  = l15 & 7;
    const int K    = 1024;

    f32x4 acc[4][4] = {};

    // staging: 16 segments of 8 rows x 64 shorts; wave handles segs 4w..4w+3
    const int lrow = lane >> 3;                 // 0..7
    const int fcol = ((lane & 7) ^ lrow) << 3;  // swizzled source granule
    const unsigned short* Ab[4];
    const unsigned short* Bb[4];
    #pragma unroll
    for (int c = 0; c < 4; ++c) {
        const int seg = 4 * wave + c;
        Ab[c] = A + (size_t)(m0 + seg * 8 + lrow) * K + fcol;
        Bb[c] = W + (size_t)(n0 + seg * 8 + lrow) * K + fcol;
    }

    for (int k0 = 0; k0 < K; k0 += 64) {
        #pragma unroll
        for (int c = 0; c < 4; ++c) {
            gload16(Ab[c] + k0, &Alds[(4 * wave + c) * 512]);
            gload16(Bb[c] + k0, &Blds[(4 * wave + c) * 512]);
        }
        __syncthreads();

        #pragma unroll
        for (int kc = 0; kc < 2; ++kc) {
            bf16x8 a[4], b[4];
            const int pg = (((kc * 4 + quad) ^ swz) << 3);
            #pragma unroll
            for (int i = 0; i < 4; ++i)
                a[i] = *(const bf16x8*)&Alds[(wm * 64 + i * 16 + l15) * 64 + pg];
            #pragma unroll
            for (int j = 0; j < 4; ++j)
                b[j] = *(const bf16x8*)&Blds[(wn * 64 + j * 16 + l15) * 64 + pg];
            #pragma unroll
            for (int i = 0; i < 4; ++i)
                #pragma unroll
                for (int j = 0; j < 4; ++j)
                    acc[i][j] = __builtin_amdgcn_mfma_f32_16x16x32_bf16(a[i], b[j], acc[i][j], 0, 0, 0);
        }
        __syncthreads();
    }

    #pragma unroll
    for (int i = 0; i < 4; ++i) {
        #pragma unroll
        for (int j = 0; j < 4; ++j) {
            const int col = n0 + wn * 64 + j * 16 + l15;
            const int row_b = m0 + wm * 64 + i * 16 + quad * 4;
            if (mode == 2) {
                #pragma unroll
                for (int r = 0; r < 4; ++r) {
                    const int row = row_b + r;
                    ((unsigned short*)outp)[(size_t)row * MROWS + col] =
                        f32_bf16(acc[i][j][r] + bias[row]);
                }
            } else if (mode == 0) {
                const float bv = bias[col];
                #pragma unroll
                for (int r = 0; r < 4; ++r)
                    ((float*)outp)[(size_t)(row_b + r) * NMODEL + col] = acc[i][j][r] + bv;
            } else {
                const float bv = bias[col];
                const int h_ = col >> 6, d_ = col & 63;
                #pragma unroll
                for (int r = 0; r < 4; ++r) {
                    const int row = row_b + r;
                    const int b_ = row >> 11, s_ = row & 2047;
                    ((unsigned short*)outp)[(((size_t)(b_ * HEADS + h_) * SEQ + s_) << 6) + d_] =
                        f32_bf16((acc[i][j][r] + bv) * scale);
                }
            }
        }
    }
}

// QKV fused: grid (512, 3). z=0: Q (scaled), z=1: K, z=2: V^T (operands swapped)
__global__ __launch_bounds__(256, 3) void gemm_qkv(
    const unsigned short* __restrict__ qb,  const unsigned short* __restrict__ wqb,
    const float* __restrict__ bq, unsigned short* __restrict__ Qp,
    const unsigned short* __restrict__ kb,  const unsigned short* __restrict__ wkb,
    const float* __restrict__ bk, unsigned short* __restrict__ Kpj,
    const unsigned short* __restrict__ wvb, const unsigned short* __restrict__ vb,
    const float* __restrict__ bv, unsigned short* __restrict__ Vtg,
    float qscale)
{
    __shared__ unsigned short Alds[128 * 64];
    __shared__ unsigned short Blds[128 * 64];
    const int bid = blockIdx.x, z = blockIdx.y;
    if (z == 0) {
        gemm128_core(qb, wqb, bq, Qp, 1, qscale, (bid >> 3) * 128, (bid & 7) * 128, Alds, Blds);
    } else if (z == 1) {
        gemm128_core(kb, wkb, bk, Kpj, 1, 1.0f, (bid >> 3) * 128, (bid & 7) * 128, Alds, Blds);
    } else {
        // M = 1024 (weights rows), N = 8192 (activation rows)
        gemm128_core(wvb, vb, bv, Vtg, 2, 1.0f, (bid & 7) * 128, (bid >> 3) * 128, Alds, Blds);
    }
}

__global__ __launch_bounds__(256, 3) void gemm_dense(
    const unsigned short* __restrict__ A, const unsigned short* __restrict__ W,
    const float* __restrict__ bias, float* __restrict__ out)
{
    __shared__ unsigned short Alds[128 * 64];
    __shared__ unsigned short Blds[128 * 64];
    const int bid = blockIdx.x;
    gemm128_core(A, W, bias, out, 0, 1.0f, (bid >> 3) * 128, (bid & 7) * 128, Alds, Blds);
}

// ---------------------------------------------------------------------------
// Flash attention, S^T formulation, no-max softmax, register-resident P.
// Grid: (S/128, B*H). 4 waves; wave owns 32 q-rows. K-tiles of 64.
// Double-buffered K/V LDS; 1 barrier per tile (T3-minimal pipeline).
//
// Slot permutation for PV: MFMA k-slot s = quad*8+j carries key
//   k = 32*kc + 16*(j>>2) + 4*quad + (j&3)
// so the B-fragment (P^T) is the lane's own S^T registers:
//   pf[i][kc] = pack(St[i][2kc][0..3], St[i][2kc+1][0..3])
// and the A-fragment (V^T) is gathered with two ds_read_b64 per fragment.
__global__ __launch_bounds__(256, 4) void attn_fwd(
    const unsigned short* __restrict__ Qp,   // [B,H,S,64] bf16, pre-scaled
    const unsigned short* __restrict__ Kp,   // [B,H,S,64] bf16
    const unsigned short* __restrict__ Vtg,  // [H*64, B*S] bf16 (transposed V)
    unsigned short* __restrict__ Op)         // [B*S,1024] bf16
{
    __shared__ unsigned short Klds[2 * 64 * 64];
    __shared__ unsigned short Vlds[2 * 64 * 64];
    const int tid  = threadIdx.x;
    const int wave = tid >> 6, lane = tid & 63;
    const int l15  = lane & 15, quad = lane >> 4;
    const int swz  = l15 & 7;
    const int bh   = blockIdx.y;
    const int b_   = bh >> 4, h_ = bh & 15;
    const int q0   = blockIdx.x * 128;

    const unsigned short* Qb = Qp + (size_t)bh * SEQ * DEPTH;
    const unsigned short* Kb = Kp + (size_t)bh * SEQ * DEPTH;
    const unsigned short* Vb = Vtg + (size_t)h_ * DEPTH * MROWS + (size_t)b_ * SEQ;

    const int srow = (wave << 3) + (lane >> 3);
    const int scg  = (lane & 7) ^ ((lane >> 3) & 7);   // swizzled source granule

    // per-lane global staging pointers (advance by kt in the loop)
    const unsigned short* Kg0 = Kb + (size_t)srow * DEPTH + scg * 8;
    const unsigned short* Kg1 = Kb + (size_t)(srow + 32) * DEPTH + scg * 8;
    const unsigned short* Vg0 = Vb + (size_t)srow * MROWS + scg * 8;
    const unsigned short* Vg1 = Vb + (size_t)(srow + 32) * MROWS + scg * 8;

    // Q B-fragments (persistent): lane holds Q[q=16i+l15][d=32kc+quad*8+j]
    bf16x8 qf[2][2];
    #pragma unroll
    for (int i = 0; i < 2; ++i)
        #pragma unroll
        for (int kc = 0; kc < 2; ++kc)
            qf[i][kc] = *(const bf16x8*)(Qb + (size_t)(q0 + wave * 32 + i * 16 + l15) * DEPTH
                                         + kc * 32 + quad * 8);

    // all-ones bf16 A-fragment for the l-sum MFMA
    union { bf16x8 v; unsigned short s[8]; } uo;
    #pragma unroll
    for (int j = 0; j < 8; ++j) uo.s[j] = 0x3F80;
    const bf16x8 ones = uo.v;

    f32x4 Ot[2][4] = {};
    f32x4 lacc[2]  = {};

    auto STAGE = [&](int buf, int kt) {
        unsigned short* KW = &Klds[buf * 4096 + wave * 512];
        unsigned short* VW = &Vlds[buf * 4096 + wave * 512];
        gload16(Kg0 + (size_t)kt * 4096, KW);
        gload16(Kg1 + (size_t)kt * 4096, KW + 2048);
        gload16(Vg0 + kt * 64, VW);
        gload16(Vg1 + kt * 64, VW + 2048);
    };

    STAGE(0, 0);
    asm volatile("s_waitcnt vmcnt(0)" ::: "memory");
    __builtin_amdgcn_s_barrier();

    for (int kt = 0; kt < SEQ / 64; ++kt) {
        const int cur = kt & 1;
        if (kt + 1 < SEQ / 64) STAGE(cur ^ 1, kt + 1);

        const unsigned short* Kc = &Klds[cur * 4096];
        const unsigned short* Vc = &Vlds[cur * 4096];

        // S^T = K Q^T (Q pre-scaled by log2e/sqrt(d))
        f32x4 St[2][4] = {};
        #pragma unroll
        for (int jj = 0; jj < 4; ++jj) {
            bf16x8 k0 = *(const bf16x8*)&Kc[(jj * 16 + l15) * 64 + ((quad ^ swz) << 3)];
            bf16x8 k1 = *(const bf16x8*)&Kc[(jj * 16 + l15) * 64 + (((4 + quad) ^ swz) << 3)];
            St[0][jj] = __builtin_amdgcn_mfma_f32_16x16x32_bf16(k0, qf[0][0], St[0][jj], 0, 0, 0);
            St[0][jj] = __builtin_amdgcn_mfma_f32_16x16x32_bf16(k1, qf[0][1], St[0][jj], 0, 0, 0);
            St[1][jj] = __builtin_amdgcn_mfma_f32_16x16x32_bf16(k0, qf[1][0], St[1][jj], 0, 0, 0);
            St[1][jj] = __builtin_amdgcn_mfma_f32_16x16x32_bf16(k1, qf[1][1], St[1][jj], 0, 0, 0);
        }

        // p = exp2(St), in place
        #pragma unroll
        for (int i = 0; i < 2; ++i)
            #pragma unroll
            for (int jj = 0; jj < 4; ++jj)
                #pragma unroll
                for (int r = 0; r < 4; ++r)
                    St[i][jj][r] = __builtin_amdgcn_exp2f(St[i][jj][r]);

        // pack P^T B-fragments in-register (permuted k-slots; no LDS, no shuffles)
        bf16x8 pf[2][2];
        #pragma unroll
        for (int i = 0; i < 2; ++i)
            #pragma unroll
            for (int kc = 0; kc < 2; ++kc) {
                union { bf16x8 v; __hip_bfloat162 h[4]; } up;
                up.h[0] = __float22bfloat162_rn(make_float2(St[i][2 * kc][0],     St[i][2 * kc][1]));
                up.h[1] = __float22bfloat162_rn(make_float2(St[i][2 * kc][2],     St[i][2 * kc][3]));
                up.h[2] = __float22bfloat162_rn(make_float2(St[i][2 * kc + 1][0], St[i][2 * kc + 1][1]));
                up.h[3] = __float22bfloat162_rn(make_float2(St[i][2 * kc + 1][2], St[i][2 * kc + 1][3]));
                pf[i][kc] = up.v;
            }

        // l += 1^T P (MFMA broadcasts the column sums to every row)
        lacc[0] = __builtin_amdgcn_mfma_f32_16x16x32_bf16(ones, pf[0][0], lacc[0], 0, 0, 0);
        lacc[0] = __builtin_amdgcn_mfma_f32_16x16x32_bf16(ones, pf[0][1], lacc[0], 0, 0, 0);
        lacc[1] = __builtin_amdgcn_mfma_f32_16x16x32_bf16(ones, pf[1][0], lacc[1], 0, 0, 0);
        lacc[1] = __builtin_amdgcn_mfma_f32_16x16x32_bf16(ones, pf[1][1], lacc[1], 0, 0, 0);

        // O^T += V^T P^T, V gathered with the same k-slot permutation:
        //   slot j<4:  key = 32kc + 4quad + j        (granule kc*4 + (quad>>1))
        //   slot j>=4: key = 32kc + 16 + 4quad + j-4 (granule kc*4 + 2 + (quad>>1))
        #pragma unroll
        for (int kc = 0; kc < 2; ++kc) {
            const int glo = ((kc * 4 + (quad >> 1)) ^ swz);
            const int ghi = ((kc * 4 + 2 + (quad >> 1)) ^ swz);
            const int sub = (quad & 1) * 4;
            #pragma unroll
            for (int dd = 0; dd < 4; ++dd) {
                const int row = (dd * 16 + l15) * 64;
                union { bf16x8 v; bf16x4 h[2]; } uv;
                uv.h[0] = *(const bf16x4*)&Vc[row + glo * 8 + sub];
                uv.h[1] = *(const bf16x4*)&Vc[row + ghi * 8 + sub];
                Ot[0][dd] = __builtin_amdgcn_mfma_f32_16x16x32_bf16(uv.v, pf[0][kc], Ot[0][dd], 0, 0, 0);
                Ot[1][dd] = __builtin_amdgcn_mfma_f32_16x16x32_bf16(uv.v, pf[1][kc], Ot[1][dd], 0, 0, 0);
            }
        }

        asm volatile("s_waitcnt vmcnt(0)" ::: "memory");
        __builtin_amdgcn_s_barrier();
    }

    // lacc[i][*] already holds the full denominator for q = i*16+l15 (all regs equal)
    #pragma unroll
    for (int i = 0; i < 2; ++i) {
        const float inv = 1.0f / lacc[i][0];
        const int row = b_ * SEQ + q0 + wave * 32 + i * 16 + l15;
        #pragma unroll
        for (int dd = 0; dd < 4; ++dd) {
            ushort4 ov;
            ov.x = f32_bf16(Ot[i][dd][0] * inv);
            ov.y = f32_bf16(Ot[i][dd][1] * inv);
            ov.z = f32_bf16(Ot[i][dd][2] * inv);
            ov.w = f32_bf16(Ot[i][dd][3] * inv);
            const int col = h_ * 64 + dd * 16 + quad * 4;
            *(ushort4*)&Op[(size_t)row * NMODEL + col] = ov;
        }
    }
}

// ---------------------------------------------------------------------------
extern "C" void kernel_launch(void* const* d_in, const int* in_sizes, int n_in,
                              void* d_out, int out_size, void* d_ws, size_t ws_size,
                              hipStream_t stream) {
    const float* q  = (const float*)d_in[0];
    const float* k  = (const float*)d_in[1];
    const float* v  = (const float*)d_in[2];
    const float* wq = (const float*)d_in[3];
    const float* bq = (const float*)d_in[4];
    const float* wk = (const float*)d_in[5];
    const float* bk = (const float*)d_in[6];
    const float* wv = (const float*)d_in[7];
    const float* bv = (const float*)d_in[8];
    const float* wd = (const float*)d_in[9];
    const float* bd = (const float*)d_in[10];

    char* ws = (char*)d_ws;
    size_t off = 0;
    auto alloc = [&](size_t bytes) { char* p = ws + off; off += bytes; return p; };
    const size_t ACT = (size_t)MROWS * NMODEL * 2;
    const size_t WGT = (size_t)NMODEL * NMODEL * 2;

    unsigned short* qb   = (unsigned short*)alloc(ACT);
    unsigned short* kb   = (unsigned short*)alloc(ACT);
    unsigned short* vb   = (unsigned short*)alloc(ACT);
    unsigned short* wqb  = (unsigned short*)alloc(WGT);
    unsigned short* wkb  = (unsigned short*)alloc(WGT);
    unsigned short* wvb  = (unsigned short*)alloc(WGT);
    unsigned short* wdb  = (unsigned short*)alloc(WGT);
    unsigned short* Qp   = (unsigned short*)alloc(ACT);
    unsigned short* Kpj  = (unsigned short*)alloc(ACT);
    unsigned short* Vtg  = (unsigned short*)alloc(ACT);   // [H*64, B*S]
    unsigned short* attn = (unsigned short*)alloc(ACT);

    const int nAct4 = MROWS * NMODEL / 4;
    const int nWgt4 = NMODEL * NMODEL / 4;
    cvt3_kernel<<<dim3(nAct4 / 256, 3), 256, 0, stream>>>(q, k, v, qb, kb, vb, nAct4);
    cvt4_kernel<<<dim3(nWgt4 / 256, 4), 256, 0, stream>>>(wq, wk, wv, wd,
                                                          wqb, wkb, wvb, wdb, nWgt4);

    const float SC = 0.18033688011112042f;   // log2(e)/sqrt(64)
    gemm_qkv<<<dim3(512, 3), 256, 0, stream>>>(qb, wqb, bq, Qp,
                                               kb, wkb, bk, Kpj,
                                               wvb, vb, bv, Vtg, SC);

    attn_fwd<<<dim3(SEQ / 128, 64), 256, 0, stream>>>(Qp, Kpj, Vtg, attn);

    gemm_dense<<<512, 256, 0, stream>>>(attn, wdb, bd, (float*)d_out);
}

// Round 3
// 321.284 us; speedup vs baseline: 1.0880x; 1.0270x over previous
//
#include <hip/hip_runtime.h>
#include <hip/hip_bf16.h>
#include <stdint.h>

// ---------------------------------------------------------------------------
// MultiHeadAttention fused forward, MI355X (gfx950)
//   B=4, S=2048, D_MODEL=1024, H=16, depth=64; fp32 I/O, bf16 MFMA internal.
// R5b (resubmit of R5 after infra failure; kernel re-audited, unchanged):
//   - wave owns 64 q-rows (was 32): K/V LDS reads and barriers per FLOP halve,
//     16 independent Ot chains per wave. Grid (8,64), 2 blocks/CU, ~220 VGPR.
//   - Vtg global token order permuted within 32-token groups (pi(k)=r+4h+8q,
//     applied in gemm mode-2 epilogue) so each lane's 8 PV keys are 16
//     contiguous bytes -> V fragment is ONE swizzled ds_read_b128 (same
//     proven pattern as K), killing the b64-gather bank conflicts of R4.
//   - softmax per 32-key subtile: exp2/pack of subtile 0 overlaps QK MFMAs of
//     subtile 1 and PV(kc=0); s_setprio(1) around MFMA clusters (T5).
//   - P still never touches LDS; l-sum still via ones-MFMA.
// ---------------------------------------------------------------------------

#define SEQ    2048
#define DEPTH  64
#define HEADS  16
#define NMODEL 1024
#define MROWS  8192   // B*S

typedef __bf16 bf16x8 __attribute__((ext_vector_type(8)));
typedef float  f32x4  __attribute__((ext_vector_type(4)));

__device__ __forceinline__ unsigned short f32_bf16(float f) {
    union { float f; unsigned int u; } c; c.f = f;
    unsigned int u = c.u + 0x7FFFu + ((c.u >> 16) & 1u);   // RNE
    return (unsigned short)(u >> 16);
}

__device__ __forceinline__ void gload16(const unsigned short* g, unsigned short* l) {
    __builtin_amdgcn_global_load_lds(
        (const __attribute__((address_space(1))) unsigned int*)g,
        (__attribute__((address_space(3))) unsigned int*)l, 16, 0, 0);
}

// ---------------------------------------------------------------------------
__global__ __launch_bounds__(256) void cvt3_kernel(
    const float* __restrict__ a, const float* __restrict__ b, const float* __restrict__ c,
    unsigned short* __restrict__ oa, unsigned short* __restrict__ ob,
    unsigned short* __restrict__ oc, int n4)
{
    const float* in; unsigned short* out;
    if (blockIdx.y == 0) { in = a; out = oa; }
    else if (blockIdx.y == 1) { in = b; out = ob; }
    else { in = c; out = oc; }
    int i = blockIdx.x * 256 + threadIdx.x;
    if (i < n4) {
        float4 f = ((const float4*)in)[i];
        ushort4 o;
        o.x = f32_bf16(f.x); o.y = f32_bf16(f.y);
        o.z = f32_bf16(f.z); o.w = f32_bf16(f.w);
        ((ushort4*)out)[i] = o;
    }
}

__global__ __launch_bounds__(256) void cvt4_kernel(
    const float* __restrict__ a, const float* __restrict__ b,
    const float* __restrict__ c, const float* __restrict__ d,
    unsigned short* __restrict__ oa, unsigned short* __restrict__ ob,
    unsigned short* __restrict__ oc, unsigned short* __restrict__ od, int n4)
{
    const float* in; unsigned short* out;
    if (blockIdx.y == 0) { in = a; out = oa; }
    else if (blockIdx.y == 1) { in = b; out = ob; }
    else if (blockIdx.y == 2) { in = c; out = oc; }
    else { in = d; out = od; }
    int i = blockIdx.x * 256 + threadIdx.x;
    if (i < n4) {
        float4 f = ((const float4*)in)[i];
        ushort4 o;
        o.x = f32_bf16(f.x); o.y = f32_bf16(f.y);
        o.z = f32_bf16(f.z); o.w = f32_bf16(f.w);
        ((ushort4*)out)[i] = o;
    }
}

// ---------------------------------------------------------------------------
// 128x128 tile GEMM core, BK=64, XOR-swizzled LDS.
// C[m,n] = sum_k A[m,k]*W[n,k]; K = 1024.
// mode 0: fp32 out row-major [.,NMODEL], bias[col]
// mode 1: bf16 out head-split [B,H,S,64], (acc+bias[col])*scale
// mode 2: bf16 out row-major [.,MROWS], bias[row]   (V^T), token order
//         permuted within 32-token groups: pi(k) = (k&3) + 4*((k>>4)&1)
//         + 8*((k>>2)&3)  -- matches attn's PV k-slot map.
__device__ __forceinline__ void gemm128_core(
    const unsigned short* __restrict__ A, const unsigned short* __restrict__ W,
    const float* __restrict__ bias, void* __restrict__ outp,
    int mode, float scale, int m0, int n0,
    unsigned short* Alds, unsigned short* Blds)
{
    const int tid  = threadIdx.x;
    const int wave = tid >> 6, lane = tid & 63;
    const int l15  = lane & 15, quad = lane >> 4;
    const int wm   = wave & 1,  wn   = wave >> 1;
    const int swz  = l15 & 7;
    const int K    = 1024;

    f32x4 acc[4][4] = {};

    // staging: 16 segments of 8 rows x 64 shorts; wave handles segs 4w..4w+3
    const int lrow = lane >> 3;                 // 0..7
    const int fcol = ((lane & 7) ^ lrow) << 3;  // swizzled source granule
    const unsigned short* Ab[4];
    const unsigned short* Bb[4];
    #pragma unroll
    for (int c = 0; c < 4; ++c) {
        const int seg = 4 * wave + c;
        Ab[c] = A + (size_t)(m0 + seg * 8 + lrow) * K + fcol;
        Bb[c] = W + (size_t)(n0 + seg * 8 + lrow) * K + fcol;
    }

    for (int k0 = 0; k0 < K; k0 += 64) {
        #pragma unroll
        for (int c = 0; c < 4; ++c) {
            gload16(Ab[c] + k0, &Alds[(4 * wave + c) * 512]);
            gload16(Bb[c] + k0, &Blds[(4 * wave + c) * 512]);
        }
        __syncthreads();

        #pragma unroll
        for (int kc = 0; kc < 2; ++kc) {
            bf16x8 a[4], b[4];
            const int pg = (((kc * 4 + quad) ^ swz) << 3);
            #pragma unroll
            for (int i = 0; i < 4; ++i)
                a[i] = *(const bf16x8*)&Alds[(wm * 64 + i * 16 + l15) * 64 + pg];
            #pragma unroll
            for (int j = 0; j < 4; ++j)
                b[j] = *(const bf16x8*)&Blds[(wn * 64 + j * 16 + l15) * 64 + pg];
            #pragma unroll
            for (int i = 0; i < 4; ++i)
                #pragma unroll
                for (int j = 0; j < 4; ++j)
                    acc[i][j] = __builtin_amdgcn_mfma_f32_16x16x32_bf16(a[i], b[j], acc[i][j], 0, 0, 0);
        }
        __syncthreads();
    }

    #pragma unroll
    for (int i = 0; i < 4; ++i) {
        #pragma unroll
        for (int j = 0; j < 4; ++j) {
            const int col = n0 + wn * 64 + j * 16 + l15;
            const int row_b = m0 + wm * 64 + i * 16 + quad * 4;
            if (mode == 2) {
                // permuted token position within its 32-group
                const int colp = (col & ~31)
                               | (col & 3)
                               | (((col >> 4) & 1) << 2)
                               | (((col >> 2) & 3) << 3);
                #pragma unroll
                for (int r = 0; r < 4; ++r) {
                    const int row = row_b + r;
                    ((unsigned short*)outp)[(size_t)row * MROWS + colp] =
                        f32_bf16(acc[i][j][r] + bias[row]);
                }
            } else if (mode == 0) {
                const float bv = bias[col];
                #pragma unroll
                for (int r = 0; r < 4; ++r)
                    ((float*)outp)[(size_t)(row_b + r) * NMODEL + col] = acc[i][j][r] + bv;
            } else {
                const float bv = bias[col];
                const int h_ = col >> 6, d_ = col & 63;
                #pragma unroll
                for (int r = 0; r < 4; ++r) {
                    const int row = row_b + r;
                    const int b_ = row >> 11, s_ = row & 2047;
                    ((unsigned short*)outp)[(((size_t)(b_ * HEADS + h_) * SEQ + s_) << 6) + d_] =
                        f32_bf16((acc[i][j][r] + bv) * scale);
                }
            }
        }
    }
}

// QKV fused: grid (512, 3). z=0: Q (scaled), z=1: K, z=2: V^T (operands swapped)
__global__ __launch_bounds__(256, 3) void gemm_qkv(
    const unsigned short* __restrict__ qb,  const unsigned short* __restrict__ wqb,
    const float* __restrict__ bq, unsigned short* __restrict__ Qp,
    const unsigned short* __restrict__ kb,  const unsigned short* __restrict__ wkb,
    const float* __restrict__ bk, unsigned short* __restrict__ Kpj,
    const unsigned short* __restrict__ wvb, const unsigned short* __restrict__ vb,
    const float* __restrict__ bv, unsigned short* __restrict__ Vtg,
    float qscale)
{
    __shared__ unsigned short Alds[128 * 64];
    __shared__ unsigned short Blds[128 * 64];
    const int bid = blockIdx.x, z = blockIdx.y;
    if (z == 0) {
        gemm128_core(qb, wqb, bq, Qp, 1, qscale, (bid >> 3) * 128, (bid & 7) * 128, Alds, Blds);
    } else if (z == 1) {
        gemm128_core(kb, wkb, bk, Kpj, 1, 1.0f, (bid >> 3) * 128, (bid & 7) * 128, Alds, Blds);
    } else {
        // M = 1024 (weights rows), N = 8192 (activation rows)
        gemm128_core(wvb, vb, bv, Vtg, 2, 1.0f, (bid & 7) * 128, (bid >> 3) * 128, Alds, Blds);
    }
}

__global__ __launch_bounds__(256, 3) void gemm_dense(
    const unsigned short* __restrict__ A, const unsigned short* __restrict__ W,
    const float* __restrict__ bias, float* __restrict__ out)
{
    __shared__ unsigned short Alds[128 * 64];
    __shared__ unsigned short Blds[128 * 64];
    const int bid = blockIdx.x;
    gemm128_core(A, W, bias, out, 0, 1.0f, (bid >> 3) * 128, (bid & 7) * 128, Alds, Blds);
}

// ---------------------------------------------------------------------------
// Flash attention, S^T formulation, no-max softmax, register-resident P.
// Grid: (S/256, B*H). 4 waves; wave owns 64 q-rows. K-tiles of 64 keys,
// processed as two 32-key subtiles so softmax of subtile 0 overlaps QK^T of
// subtile 1. Double-buffered K/V LDS; 1 barrier per tile.
//
// PV k-slot map: slot s = quad*8+j of the PV MFMA for subtile `half` carries
//   key k = 32*half + 16*(j>>2) + 4*quad + (j&3)
// P B-fragment = lane's own S^T registers (no LDS, no shuffles).
// Vtg's global token order is pre-permuted (pi above) so the V A-fragment is
// ONE swizzled ds_read_b128 at granule (half*4+quad)^swz -- same pattern as K.
__global__ __launch_bounds__(256, 2) void attn_fwd(
    const unsigned short* __restrict__ Qp,   // [B,H,S,64] bf16, pre-scaled
    const unsigned short* __restrict__ Kp,   // [B,H,S,64] bf16
    const unsigned short* __restrict__ Vtg,  // [H*64, B*S] bf16, token-permuted
    unsigned short* __restrict__ Op)         // [B*S,1024] bf16
{
    __shared__ unsigned short Klds[2 * 64 * 64];
    __shared__ unsigned short Vlds[2 * 64 * 64];
    const int tid  = threadIdx.x;
    const int wave = tid >> 6, lane = tid & 63;
    const int l15  = lane & 15, quad = lane >> 4;
    const int swz  = l15 & 7;
    const int bh   = blockIdx.y;
    const int b_   = bh >> 4, h_ = bh & 15;
    const int q0   = blockIdx.x * 256;

    const unsigned short* Qb = Qp + (size_t)bh * SEQ * DEPTH;
    const unsigned short* Kb = Kp + (size_t)bh * SEQ * DEPTH;
    const unsigned short* Vb = Vtg + (size_t)h_ * DEPTH * MROWS + (size_t)b_ * SEQ;

    const int srow = (wave << 3) + (lane >> 3);
    const int scg  = (lane & 7) ^ ((lane >> 3) & 7);   // swizzled source granule

    const unsigned short* Kg0 = Kb + (size_t)srow * DEPTH + scg * 8;
    const unsigned short* Kg1 = Kb + (size_t)(srow + 32) * DEPTH + scg * 8;
    const unsigned short* Vg0 = Vb + (size_t)srow * MROWS + scg * 8;
    const unsigned short* Vg1 = Vb + (size_t)(srow + 32) * MROWS + scg * 8;

    // Q B-fragments (persistent): lane holds Q[q=16i+l15][d=32kc+quad*8+j]
    bf16x8 qf[4][2];
    #pragma unroll
    for (int i = 0; i < 4; ++i)
        #pragma unroll
        for (int kc = 0; kc < 2; ++kc)
            qf[i][kc] = *(const bf16x8*)(Qb + (size_t)(q0 + wave * 64 + i * 16 + l15) * DEPTH
                                         + kc * 32 + quad * 8);

    // all-ones bf16 A-fragment for the l-sum MFMA
    union { bf16x8 v; unsigned short s[8]; } uo;
    #pragma unroll
    for (int j = 0; j < 8; ++j) uo.s[j] = 0x3F80;
    const bf16x8 ones = uo.v;

    f32x4 Ot[4][4] = {};
    f32x4 lacc[4]  = {};

    auto STAGE = [&](int buf, int kt) {
        unsigned short* KW = &Klds[buf * 4096 + wave * 512];
        unsigned short* VW = &Vlds[buf * 4096 + wave * 512];
        gload16(Kg0 + (size_t)kt * 4096, KW);
        gload16(Kg1 + (size_t)kt * 4096, KW + 2048);
        gload16(Vg0 + kt * 64, VW);
        gload16(Vg1 + kt * 64, VW + 2048);
    };

    STAGE(0, 0);
    asm volatile("s_waitcnt vmcnt(0)" ::: "memory");
    __builtin_amdgcn_s_barrier();

    for (int kt = 0; kt < SEQ / 64; ++kt) {
        const int cur = kt & 1;
        if (kt + 1 < SEQ / 64) STAGE(cur ^ 1, kt + 1);

        const unsigned short* Kc = &Klds[cur * 4096];

        // two 32-key subtiles; subtile `half` covers keys 64kt+32half..+31
        #pragma unroll
        for (int half = 0; half < 2; ++half) {
            // ---- QK^T MFMA cluster (keys 32half..32half+31) ----
            __builtin_amdgcn_s_setprio(1);
            const int r0 = (2 * half) * 16 + l15;
            const int r1 = (2 * half + 1) * 16 + l15;
            bf16x8 ka0 = *(const bf16x8*)&Kc[r0 * 64 + ((quad ^ swz) << 3)];
            bf16x8 ka1 = *(const bf16x8*)&Kc[r0 * 64 + (((4 + quad) ^ swz) << 3)];
            bf16x8 kb0 = *(const bf16x8*)&Kc[r1 * 64 + ((quad ^ swz) << 3)];
            bf16x8 kb1 = *(const bf16x8*)&Kc[r1 * 64 + (((4 + quad) ^ swz) << 3)];
            f32x4 S0[4], S1[4];
            #pragma unroll
            for (int i = 0; i < 4; ++i) {
                S0[i] = f32x4{};
                S0[i] = __builtin_amdgcn_mfma_f32_16x16x32_bf16(ka0, qf[i][0], S0[i], 0, 0, 0);
                S0[i] = __builtin_amdgcn_mfma_f32_16x16x32_bf16(ka1, qf[i][1], S0[i], 0, 0, 0);
                S1[i] = f32x4{};
                S1[i] = __builtin_amdgcn_mfma_f32_16x16x32_bf16(kb0, qf[i][0], S1[i], 0, 0, 0);
                S1[i] = __builtin_amdgcn_mfma_f32_16x16x32_bf16(kb1, qf[i][1], S1[i], 0, 0, 0);
            }
            __builtin_amdgcn_s_setprio(0);

            // ---- softmax: p = exp2(S), pack P B-fragments in-register ----
            bf16x8 pfh[4];
            #pragma unroll
            for (int i = 0; i < 4; ++i) {
                float e0 = __builtin_amdgcn_exp2f(S0[i][0]);
                float e1 = __builtin_amdgcn_exp2f(S0[i][1]);
                float e2 = __builtin_amdgcn_exp2f(S0[i][2]);
                float e3 = __builtin_amdgcn_exp2f(S0[i][3]);
                float e4 = __builtin_amdgcn_exp2f(S1[i][0]);
                float e5 = __builtin_amdgcn_exp2f(S1[i][1]);
                float e6 = __builtin_amdgcn_exp2f(S1[i][2]);
                float e7 = __builtin_amdgcn_exp2f(S1[i][3]);
                union { bf16x8 v; __hip_bfloat162 h[4]; } up;
                up.h[0] = __float22bfloat162_rn(make_float2(e0, e1));
                up.h[1] = __float22bfloat162_rn(make_float2(e2, e3));
                up.h[2] = __float22bfloat162_rn(make_float2(e4, e5));
                up.h[3] = __float22bfloat162_rn(make_float2(e6, e7));
                pfh[i] = up.v;
            }

            // ---- l-sum + PV MFMA cluster ----
            __builtin_amdgcn_s_setprio(1);
            lacc[0] = __builtin_amdgcn_mfma_f32_16x16x32_bf16(ones, pfh[0], lacc[0], 0, 0, 0);
            lacc[1] = __builtin_amdgcn_mfma_f32_16x16x32_bf16(ones, pfh[1], lacc[1], 0, 0, 0);
            lacc[2] = __builtin_amdgcn_mfma_f32_16x16x32_bf16(ones, pfh[2], lacc[2], 0, 0, 0);
            lacc[3] = __builtin_amdgcn_mfma_f32_16x16x32_bf16(ones, pfh[3], lacc[3], 0, 0, 0);
            #pragma unroll
            for (int dd = 0; dd < 4; ++dd) {
                bf16x8 vf = *(const bf16x8*)&Vlds[cur * 4096 +
                            (dd * 16 + l15) * 64 + (((half * 4 + quad) ^ swz) << 3)];
                #pragma unroll
                for (int i = 0; i < 4; ++i)
                    Ot[i][dd] = __builtin_amdgcn_mfma_f32_16x16x32_bf16(vf, pfh[i], Ot[i][dd], 0, 0, 0);
            }
            __builtin_amdgcn_s_setprio(0);
        }

        asm volatile("s_waitcnt vmcnt(0)" ::: "memory");
        __builtin_amdgcn_s_barrier();
    }

    // lacc[i][*] already holds the full denominator for q = i*16+l15
    #pragma unroll
    for (int i = 0; i < 4; ++i) {
        const float inv = 1.0f / lacc[i][0];
        const int row = b_ * SEQ + q0 + wave * 64 + i * 16 + l15;
        #pragma unroll
        for (int dd = 0; dd < 4; ++dd) {
            ushort4 ov;
            ov.x = f32_bf16(Ot[i][dd][0] * inv);
            ov.y = f32_bf16(Ot[i][dd][1] * inv);
            ov.z = f32_bf16(Ot[i][dd][2] * inv);
            ov.w = f32_bf16(Ot[i][dd][3] * inv);
            const int col = h_ * 64 + dd * 16 + quad * 4;
            *(ushort4*)&Op[(size_t)row * NMODEL + col] = ov;
        }
    }
}

// ---------------------------------------------------------------------------
extern "C" void kernel_launch(void* const* d_in, const int* in_sizes, int n_in,
                              void* d_out, int out_size, void* d_ws, size_t ws_size,
                              hipStream_t stream) {
    const float* q  = (const float*)d_in[0];
    const float* k  = (const float*)d_in[1];
    const float* v  = (const float*)d_in[2];
    const float* wq = (const float*)d_in[3];
    const float* bq = (const float*)d_in[4];
    const float* wk = (const float*)d_in[5];
    const float* bk = (const float*)d_in[6];
    const float* wv = (const float*)d_in[7];
    const float* bv = (const float*)d_in[8];
    const float* wd = (const float*)d_in[9];
    const float* bd = (const float*)d_in[10];

    char* ws = (char*)d_ws;
    size_t off = 0;
    auto alloc = [&](size_t bytes) { char* p = ws + off; off += bytes; return p; };
    const size_t ACT = (size_t)MROWS * NMODEL * 2;
    const size_t WGT = (size_t)NMODEL * NMODEL * 2;

    unsigned short* qb   = (unsigned short*)alloc(ACT);
    unsigned short* kb   = (unsigned short*)alloc(ACT);
    unsigned short* vb   = (unsigned short*)alloc(ACT);
    unsigned short* wqb  = (unsigned short*)alloc(WGT);
    unsigned short* wkb  = (unsigned short*)alloc(WGT);
    unsigned short* wvb  = (unsigned short*)alloc(WGT);
    unsigned short* wdb  = (unsigned short*)alloc(WGT);
    unsigned short* Qp   = (unsigned short*)alloc(ACT);
    unsigned short* Kpj  = (unsigned short*)alloc(ACT);
    unsigned short* Vtg  = (unsigned short*)alloc(ACT);   // [H*64, B*S], token-permuted
    unsigned short* attn = (unsigned short*)alloc(ACT);

    const int nAct4 = MROWS * NMODEL / 4;
    const int nWgt4 = NMODEL * NMODEL / 4;
    cvt3_kernel<<<dim3(nAct4 / 256, 3), 256, 0, stream>>>(q, k, v, qb, kb, vb, nAct4);
    cvt4_kernel<<<dim3(nWgt4 / 256, 4), 256, 0, stream>>>(wq, wk, wv, wd,
                                                          wqb, wkb, wvb, wdb, nWgt4);

    const float SC = 0.18033688011112042f;   // log2(e)/sqrt(64)
    gemm_qkv<<<dim3(512, 3), 256, 0, stream>>>(qb, wqb, bq, Qp,
                                               kb, wkb, bk, Kpj,
                                               wvb, vb, bv, Vtg, SC);

    attn_fwd<<<dim3(SEQ / 256, 64), 256, 0, stream>>>(Qp, Kpj, Vtg, attn);

    gemm_dense<<<512, 256, 0, stream>>>(attn, wdb, bd, (float*)d_out);
}